// Round 5
// baseline (181.632 us; speedup 1.0000x reference)
//
#include <hip/hip_runtime.h>
#include <math.h>

#define NPTS 16384
#define NPTS_PAD 16896       // +512 float4 pad per batch for scan prefetch
#define KN 32
#define C 256
#define NQ 8192              // 8 * 1024 queries
#define PF_ELEMS (NQ * C)

#define W1P_ELEMS (3 * 16 * 64 * 8)                 // 24576  (Ktiles=3, Ntiles=16)
#define W2P_ELEMS (8 * 16 * 64 * 8)                 // 65536  (Ktiles=8)
#define WP_ELEMS  (W1P_ELEMS + W2P_ELEMS)           // 90112 halves = 180224 B (16-aligned)
#define XYZW_ELEMS (8 * NPTS_PAD)                   // 135168 float4
#define HSTR 264                                    // halves per H16 row

typedef _Float16 half8 __attribute__((ext_vector_type(8)));
typedef _Float16 half4v __attribute__((ext_vector_type(4)));
typedef _Float16 half2t __attribute__((ext_vector_type(2)));
typedef float f32x4 __attribute__((ext_vector_type(4)));

__device__ __forceinline__ float fdot2f(half2t a, half2t b, float c) {
#if __has_builtin(__builtin_amdgcn_fdot2)
    return __builtin_amdgcn_fdot2(a, b, c, false);
#else
    return fmaf((float)a[1], (float)b[1], fmaf((float)a[0], (float)b[0], c));
#endif
}

__device__ __forceinline__ float exp2f_fast(float x) {
#if __has_builtin(__builtin_amdgcn_exp2f)
    return __builtin_amdgcn_exp2f(x);
#else
    return exp2f(x);
#endif
}

// tanh-approx GeLU, exp2-folded: y = x - x/(2^(x*p2L)+1), p2L = p2 * log2(e).
// 7 VALU ops (2 transcendental); max err ~3e-4 (same poly as before).
__device__ __forceinline__ float gelu_tanh(float x) {
    const float t  = x * x;
    const float p2 = fmaf(t, 0.10294324f, 2.3022083f);   // {0.07135482, 1.59576912} * log2e
    const float e  = exp2f_fast(x * p2);
    return fmaf(-x, __builtin_amdgcn_rcpf(e + 1.0f), x);
}

// ---------------------------------------------------------------------------
// Prep: pack W1 (91x256 + b1 folded at k=91, K-padded to 96) and W2 (256x256)
// into f16 fragment order; pack xyz into float4 (x,y,z,|p|^2) with the EXACT
// rounding sequence the encoder's ball query uses (bit-identical membership).
// xyzw is padded per batch to NPTS_PAD (scan prefetch overruns by <=512).
//   flat = ((kt*16 + nt)*64 + lane)*8 + j
//   k = kt*32 + (lane>>4)*8 + j ;  ch = nt*16 + (lane&15)
// ---------------------------------------------------------------------------
__global__ void prep_kernel(const float* __restrict__ W1,
                            const float* __restrict__ b1,
                            const float* __restrict__ W2,
                            const float* __restrict__ xyz,
                            _Float16* __restrict__ wp,
                            float4* __restrict__ xyzw) {
    const int idx = blockIdx.x * 256 + threadIdx.x;   // 0 .. 225279
    if (idx < 96 * 256) {
        const int k = idx >> 8, n = idx & 255;
        const float v = (k < 91) ? W1[k * 256 + n] : ((k == 91) ? b1[n] : 0.0f);
        const int kt = k >> 5, quad = (k >> 3) & 3, j = k & 7;
        const int nt = n >> 4, l15 = n & 15;
        wp[(((kt * 16 + nt) * 64) + quad * 16 + l15) * 8 + j] = (_Float16)v;
    } else if (idx < WP_ELEMS) {
        const int e = idx - 96 * 256;
        const int k = e >> 8, n = e & 255;
        const int kt = k >> 5, quad = (k >> 3) & 3, j = k & 7;
        const int nt = n >> 4, l15 = n & 15;
        wp[W1P_ELEMS + (((kt * 16 + nt) * 64) + quad * 16 + l15) * 8 + j] =
            (_Float16)W2[k * 256 + n];
    } else {
        const int e  = idx - WP_ELEMS;                // 0 .. 135167
        const int bb = e / NPTS_PAD;
        const int off = e - bb * NPTS_PAD;
        float4 v;
        if (off < NPTS) {
            const float px = xyz[((size_t)bb * NPTS + off) * 3 + 0];
            const float py = xyz[((size_t)bb * NPTS + off) * 3 + 1];
            const float pz = xyz[((size_t)bb * NPTS + off) * 3 + 2];
            const float sp = __fadd_rn(__fadd_rn(__fmul_rn(px, px), __fmul_rn(py, py)),
                                       __fmul_rn(pz, pz));
            v = make_float4(px, py, pz, sp);
        } else {
            v = make_float4(1e9f, 1e9f, 1e9f, 3e18f);  // sentinel pad (never in-ball)
        }
        xyzw[(size_t)bb * NPTS_PAD + off] = v;
    }
}

// ---------------------------------------------------------------------------
// Fused: ball-query + gather/posenc + MLP1(LN,GeLU) + MLP2(LN) + max.
// Round-18 (session R5): VALU-cut on the saturated-issue regime.
//  * R4 post-mortem: VALUBusy 63 + MfmaUtil 21 = 84% combined issue ->
//    issue-bound; wall scales with instruction count now.
//  * GeLU exp2-folded (9 -> 7 ops/eval, 64 evals/thread).
//  * b2 folded into GEMM2 acc init (C-in = b2) -> kills 64-add pass.
//  * LN2 packed-f16 (R2-proven numerics): cvt acc->f16 pairs once (acc dies),
//    stats via fdot2 on f16 pairs, apply via v_pk_mul/v_pk_fma.
//  * ball-query prefix sums scalarized via readfirstlane (SALU pipe, wave-
//    uniform values).
//  * keeps R1-R4: 2 queries/block, saddr weight loads, packed (x,y,z,|p|^2),
//    branchless posenc, Xs/H16 overlay, fused LN epilogues, (256,4).
// No runtime-indexed private arrays (all under full unroll, const indices).
// ---------------------------------------------------------------------------
__global__ void __launch_bounds__(256, 4)
encoder_fused(const float4* __restrict__ xyzw,
              const float* __restrict__ pf,
              const float* __restrict__ ctr,
              const float* __restrict__ g1, const float* __restrict__ be1,
              const float* __restrict__ b2, const float* __restrict__ g2,
              const float* __restrict__ be2,
              const _Float16* __restrict__ w1p,
              const _Float16* __restrict__ w2p,
              float* __restrict__ out0,      // patch_feature [8192][256]
              float* __restrict__ out1) {    // neighbor idx as float [8192][32]
    const int q0 = blockIdx.x * 2;           // queries q0, q0+1 (same batch b)
    const int b = q0 >> 10;
    const int t = threadIdx.x;
    const int w = t >> 6;
    const int lane = t & 63;
    const int quad = lane >> 4;
    const int l15  = lane & 15;

    __shared__ __align__(16) unsigned char H16raw[2][KN * HSTR * 2];  // 33792
    __shared__ __align__(16) _Float16 lnph[4 * 256];                  // 2048
    __shared__ __align__(16) float2 sred[2][2][16][4];                // 2048: [qq][mt][l15][w]
    __shared__ int nbr[2][KN];                                        // 256
    __shared__ int wcnt[2][2][2][4];                                  // [par][qq][grp][warp]

    _Float16 (*H16a)[HSTR] = (_Float16(*)[HSTR])H16raw[0];
    _Float16 (*H16b)[HSTR] = (_Float16(*)[HSTR])H16raw[1];
    _Float16 (*Xs0)[104]   = (_Float16(*)[104])H16raw[0];   // OVERLAY
    _Float16 (*Xs1)[104]   = (_Float16(*)[104])H16raw[1];   // OVERLAY
    _Float16* g1h  = lnph;
    _Float16* be1h = lnph + 256;
    _Float16* g2h  = lnph + 512;
    _Float16* be2h = lnph + 768;

    lnph[t]       = (_Float16)g1[t];
    lnph[256 + t] = (_Float16)be1[t];
    lnph[512 + t] = (_Float16)g2[t];
    lnph[768 + t] = (_Float16)be2[t];

    // ---- Phase 0: shared ball query for both centers, 512 pts/iter ----
    const float4* xwb = xyzw + (size_t)b * NPTS_PAD;
    const float cxA = ctr[q0 * 3 + 0], cyA = ctr[q0 * 3 + 1], czA = ctr[q0 * 3 + 2];
    const float cxB = ctr[q0 * 3 + 3], cyB = ctr[q0 * 3 + 4], czB = ctr[q0 * 3 + 5];
    const float scA = __fadd_rn(__fadd_rn(__fmul_rn(cxA, cxA), __fmul_rn(cyA, cyA)),
                                __fmul_rn(czA, czA));
    const float scB = __fadd_rn(__fadd_rn(__fmul_rn(cxB, cxB), __fmul_rn(cyB, cyB)),
                                __fmul_rn(czB, czB));

    float4 pw0 = xwb[t];
    float4 pw1 = xwb[256 + t];
    int foundA = 0, foundB = 0;
    int par = 0;
    for (int base = 0; base < NPTS; base += 512) {
        // prefetch next iteration (pad guarantees in-bounds; unused at tail)
        const float4 nx0 = xwb[base + 512 + t];
        const float4 nx1 = xwb[base + 768 + t];

        const float dA0 = __fadd_rn(__fadd_rn(__fmul_rn(cxA, pw0.x), __fmul_rn(cyA, pw0.y)),
                                    __fmul_rn(czA, pw0.z));
        const float sA0 = __fsub_rn(__fadd_rn(scA, pw0.w), __fmul_rn(2.0f, dA0));
        const float dA1 = __fadd_rn(__fadd_rn(__fmul_rn(cxA, pw1.x), __fmul_rn(cyA, pw1.y)),
                                    __fmul_rn(czA, pw1.z));
        const float sA1 = __fsub_rn(__fadd_rn(scA, pw1.w), __fmul_rn(2.0f, dA1));
        const float dB0 = __fadd_rn(__fadd_rn(__fmul_rn(cxB, pw0.x), __fmul_rn(cyB, pw0.y)),
                                    __fmul_rn(czB, pw0.z));
        const float sB0 = __fsub_rn(__fadd_rn(scB, pw0.w), __fmul_rn(2.0f, dB0));
        const float dB1 = __fadd_rn(__fadd_rn(__fmul_rn(cxB, pw1.x), __fmul_rn(cyB, pw1.y)),
                                    __fmul_rn(czB, pw1.z));
        const float sB1 = __fsub_rn(__fadd_rn(scB, pw1.w), __fmul_rn(2.0f, dB1));
        const bool iA0 = (sA0 <= 0.0625f);
        const bool iA1 = (sA1 <= 0.0625f);
        const bool iB0 = (sB0 <= 0.0625f);
        const bool iB1 = (sB1 <= 0.0625f);

        const unsigned long long mA0 = __ballot(iA0);
        const unsigned long long mA1 = __ballot(iA1);
        const unsigned long long mB0 = __ballot(iB0);
        const unsigned long long mB1 = __ballot(iB1);
        if (lane == 0) {
            wcnt[par][0][0][w] = (int)__popcll(mA0);
            wcnt[par][0][1][w] = (int)__popcll(mA1);
            wcnt[par][1][0][w] = (int)__popcll(mB0);
            wcnt[par][1][1][w] = (int)__popcll(mB1);
        }
        __syncthreads();
        const unsigned long long lmask = (1ull << lane) - 1ull;
        {   // query A compaction (counts are wave-uniform -> SALU via rfl)
            const int c00 = __builtin_amdgcn_readfirstlane(wcnt[par][0][0][0]);
            const int c01 = __builtin_amdgcn_readfirstlane(wcnt[par][0][0][1]);
            const int c02 = __builtin_amdgcn_readfirstlane(wcnt[par][0][0][2]);
            const int c03 = __builtin_amdgcn_readfirstlane(wcnt[par][0][0][3]);
            const int c10 = __builtin_amdgcn_readfirstlane(wcnt[par][0][1][0]);
            const int c11 = __builtin_amdgcn_readfirstlane(wcnt[par][0][1][1]);
            const int c12 = __builtin_amdgcn_readfirstlane(wcnt[par][0][1][2]);
            const int c13 = __builtin_amdgcn_readfirstlane(wcnt[par][0][1][3]);
            int pre0 = foundA;
            if (w > 0) pre0 += c00;
            if (w > 1) pre0 += c01;
            if (w > 2) pre0 += c02;
            const int C0 = c00 + c01 + c02 + c03;
            int pre1 = foundA + C0;
            if (w > 0) pre1 += c10;
            if (w > 1) pre1 += c11;
            if (w > 2) pre1 += c12;
            const int pos0 = pre0 + (int)__popcll(mA0 & lmask);
            const int pos1 = pre1 + (int)__popcll(mA1 & lmask);
            if (iA0 && pos0 < KN) nbr[0][pos0] = base + t;
            if (iA1 && pos1 < KN) nbr[0][pos1] = base + 256 + t;
            foundA += C0 + c10 + c11 + c12 + c13;   // block-uniform
        }
        {   // query B compaction
            const int c00 = __builtin_amdgcn_readfirstlane(wcnt[par][1][0][0]);
            const int c01 = __builtin_amdgcn_readfirstlane(wcnt[par][1][0][1]);
            const int c02 = __builtin_amdgcn_readfirstlane(wcnt[par][1][0][2]);
            const int c03 = __builtin_amdgcn_readfirstlane(wcnt[par][1][0][3]);
            const int c10 = __builtin_amdgcn_readfirstlane(wcnt[par][1][1][0]);
            const int c11 = __builtin_amdgcn_readfirstlane(wcnt[par][1][1][1]);
            const int c12 = __builtin_amdgcn_readfirstlane(wcnt[par][1][1][2]);
            const int c13 = __builtin_amdgcn_readfirstlane(wcnt[par][1][1][3]);
            int pre0 = foundB;
            if (w > 0) pre0 += c00;
            if (w > 1) pre0 += c01;
            if (w > 2) pre0 += c02;
            const int C0 = c00 + c01 + c02 + c03;
            int pre1 = foundB + C0;
            if (w > 0) pre1 += c10;
            if (w > 1) pre1 += c11;
            if (w > 2) pre1 += c12;
            const int pos0 = pre0 + (int)__popcll(mB0 & lmask);
            const int pos1 = pre1 + (int)__popcll(mB1 & lmask);
            if (iB0 && pos0 < KN) nbr[1][pos0] = base + t;
            if (iB1 && pos1 < KN) nbr[1][pos1] = base + 256 + t;
            foundB += C0 + c10 + c11 + c12 + c13;   // block-uniform
        }
        par ^= 1;
        if (foundA >= KN && foundB >= KN) break;
        pw0 = nx0;
        pw1 = nx1;
    }
    __syncthreads();                  // nbr visible to all
    const int cntA = (foundA < KN) ? foundA : KN;
    const int cntB = (foundB < KN) ? foundB : KN;
    const int fstA = (cntA > 0) ? nbr[0][0] : NPTS;
    const int fstB = (cntB > 0) ? nbr[1][0] : NPTS;

    if (t < 2 * KN) {
        const int qq = t >> 5, i = t & 31;
        const int cnt = qq ? cntB : cntA;
        const int fst = qq ? fstB : fstA;
        out1[(size_t)(q0 + qq) * KN + i] = (float)((i < cnt) ? nbr[qq][i] : fst);
    }

    // ---- Phase 1: gather + rel + posenc into XsQ (k=91 is 1.0 for b1) ----
    #pragma unroll
    for (int qq = 0; qq < 2; ++qq) {
        const int k  = t >> 3;
        const int tc = t & 7;
        const int cnt = qq ? cntB : cntA;
        const int fst = qq ? fstB : fstA;
        const float ccx = qq ? cxB : cxA;
        const float ccy = qq ? cyB : cyA;
        const float ccz = qq ? czB : czA;
        const int nidx = (k < cnt) ? nbr[qq][k] : fst;
        const int n = (nidx < NPTS) ? nidx : NPTS - 1;   // JAX OOB gather clamp
        const float4 pw = xwb[n];
        const float rx = pw.x - ccx;
        const float ry = pw.y - ccy;
        const float rz = pw.z - ccz;
        const float* pfr = pf + ((size_t)b * NPTS + n) * 64;

        const float4 f0 = *(const float4*)(pfr + tc * 8);
        const float4 f1 = *(const float4*)(pfr + tc * 8 + 4);
        half8 hv;
        hv[0] = (_Float16)f0.x; hv[1] = (_Float16)f0.y;
        hv[2] = (_Float16)f0.z; hv[3] = (_Float16)f0.w;
        hv[4] = (_Float16)f1.x; hv[5] = (_Float16)f1.y;
        hv[6] = (_Float16)f1.z; hv[7] = (_Float16)f1.w;
        if (qq == 0) *(half8*)&Xs0[k][tc * 8] = hv;
        else         *(half8*)&Xs1[k][tc * 8] = hv;

        half4v ov;
        #pragma unroll
        for (int j = 0; j < 4; ++j) {
            const int cm = tc * 4 + j;          // 0..31
            const int jj = cm - 3;
            const int d  = jj >> 3;
            const int mm = jj & 7;
            const float rsel = (d == 0) ? rx : ((d == 1) ? ry : rz);
            const float f2 = __int_as_float(0x3E22F983 + ((mm & 3) << 23));
            const float arg = fmaf(rsel, f2, (mm >= 4) ? 0.25f : 0.0f);
#if __has_builtin(__builtin_amdgcn_sinf)
            const float sv = __builtin_amdgcn_sinf(arg);
#else
            const float sv = __sinf(arg * 6.2831853071795864f);
#endif
            float v = (cm < 3) ? ((cm == 0) ? rx : ((cm == 1) ? ry : rz)) : sv;
            v = (cm == 27) ? 1.0f : ((cm > 27) ? 0.0f : v);
            ov[j] = (_Float16)v;
        }
        if (qq == 0) *(half4v*)&Xs0[k][64 + tc * 4] = ov;
        else         *(half4v*)&Xs1[k][64 + tc * 4] = ov;
    }
    __syncthreads();

    f32x4 acc[2][2][4];   // [qq][mt][nt]; lane: ch=(w*4+nt)*16+quad*4+r, pt=mt*16+l15

    // uniform (SGPR) weight bases + per-lane voffset -> saddr-form loads
    const int wu = __builtin_amdgcn_readfirstlane(w);
    const _Float16* __restrict__ w1w = w1p + (size_t)(wu * 4) * 512;
    const _Float16* __restrict__ w2w = w2p + (size_t)(wu * 4) * 512;
    const int lo8 = lane * 8;

    // ---- GEMM1: W1^T as A, Xs{0,1} as B -> acc (b1 via folded row) ----
    #pragma unroll
    for (int qq = 0; qq < 2; ++qq)
        #pragma unroll
        for (int mt = 0; mt < 2; ++mt)
            #pragma unroll
            for (int nt = 0; nt < 4; ++nt)
                acc[qq][mt][nt] = (f32x4){0.f, 0.f, 0.f, 0.f};

    #pragma unroll
    for (int kt = 0; kt < 3; ++kt) {
        const half8 xA0 = *(const half8*)&Xs0[l15][kt * 32 + quad * 8];
        const half8 xA1 = *(const half8*)&Xs0[16 + l15][kt * 32 + quad * 8];
        const half8 xB0 = *(const half8*)&Xs1[l15][kt * 32 + quad * 8];
        const half8 xB1 = *(const half8*)&Xs1[16 + l15][kt * 32 + quad * 8];
        #pragma unroll
        for (int nt = 0; nt < 4; ++nt) {
            const half8 wf = *(const half8*)(w1w + (kt * 16 + nt) * 512 + lo8);
            acc[0][0][nt] = __builtin_amdgcn_mfma_f32_16x16x32_f16(wf, xA0, acc[0][0][nt], 0, 0, 0);
            acc[0][1][nt] = __builtin_amdgcn_mfma_f32_16x16x32_f16(wf, xA1, acc[0][1][nt], 0, 0, 0);
            acc[1][0][nt] = __builtin_amdgcn_mfma_f32_16x16x32_f16(wf, xB0, acc[1][0][nt], 0, 0, 0);
            acc[1][1][nt] = __builtin_amdgcn_mfma_f32_16x16x32_f16(wf, xB1, acc[1][1][nt], 0, 0, 0);
        }
    }

    // b2 fragments for GEMM2 C-init (issued early, consumed after LN1)
    f32x4 bv[4];
    #pragma unroll
    for (int nt = 0; nt < 4; ++nt)
        bv[nt] = *(const f32x4*)&b2[(w * 4 + nt) * 16 + quad * 4];

    // ---- LN1 stats on f32 accs (in-register + quad shfl + cross-warp LDS) ----
    float mu[2][2], rs[2][2];
    #pragma unroll
    for (int qq = 0; qq < 2; ++qq)
        #pragma unroll
        for (int mt = 0; mt < 2; ++mt) {
            float s = 0.0f, s2 = 0.0f;
            #pragma unroll
            for (int nt = 0; nt < 4; ++nt)
                #pragma unroll
                for (int r = 0; r < 4; ++r) {
                    const float v = acc[qq][mt][nt][r];
                    s += v;
                    s2 = fmaf(v, v, s2);
                }
            s  += __shfl_xor(s, 16, 64);  s  += __shfl_xor(s, 32, 64);
            s2 += __shfl_xor(s2, 16, 64); s2 += __shfl_xor(s2, 32, 64);
            if (quad == 0) sred[qq][mt][l15][w] = make_float2(s, s2);
        }
    __syncthreads();   // overlay fence (Xs reads done) + sred partials visible
    #pragma unroll
    for (int qq = 0; qq < 2; ++qq)
        #pragma unroll
        for (int mt = 0; mt < 2; ++mt) {
            const float4 pA = *(const float4*)&sred[qq][mt][l15][0];
            const float4 pB = *(const float4*)&sred[qq][mt][l15][2];
            const float S = pA.x + pA.z + pB.x + pB.z;
            const float Q = pA.y + pA.w + pB.y + pB.w;
            const float m_ = S * (1.0f / 256.0f);
            const float var = fmaf(Q, 1.0f / 256.0f, -m_ * m_);
            mu[qq][mt] = m_;
            rs[qq][mt] = __builtin_amdgcn_rsqf(var + 1e-5f);
        }

    // ---- LN1 apply + GeLU in f32, single f16 store into H16 ----
    #pragma unroll
    for (int nt = 0; nt < 4; ++nt) {
        const int chb = (w * 4 + nt) * 16 + quad * 4;
        const half4v g4h  = *(const half4v*)&g1h[chb];
        const half4v be4h = *(const half4v*)&be1h[chb];
        #pragma unroll
        for (int qq = 0; qq < 2; ++qq)
            #pragma unroll
            for (int mt = 0; mt < 2; ++mt) {
                half4v h;
                #pragma unroll
                for (int r = 0; r < 4; ++r) {
                    const float A = (float)g4h[r] * rs[qq][mt];
                    const float y = fmaf(acc[qq][mt][nt][r] - mu[qq][mt], A, (float)be4h[r]);
                    h[r] = (_Float16)gelu_tanh(y);
                }
                if (qq == 0) *(half4v*)&H16a[mt * 16 + l15][chb] = h;
                else         *(half4v*)&H16b[mt * 16 + l15][chb] = h;
            }
    }
    __syncthreads();   // H16 ready for GEMM2 B-reads

    // ---- GEMM2: W2^T as A, H{a,b} as B; C-init = b2 (fold) ----
    #pragma unroll
    for (int qq = 0; qq < 2; ++qq)
        #pragma unroll
        for (int mt = 0; mt < 2; ++mt)
            #pragma unroll
            for (int nt = 0; nt < 4; ++nt)
                acc[qq][mt][nt] = bv[nt];

    #pragma unroll
    for (int kt = 0; kt < 8; ++kt) {
        const half8 hA0 = *(const half8*)&H16a[l15][kt * 32 + quad * 8];
        const half8 hA1 = *(const half8*)&H16a[16 + l15][kt * 32 + quad * 8];
        const half8 hB0 = *(const half8*)&H16b[l15][kt * 32 + quad * 8];
        const half8 hB1 = *(const half8*)&H16b[16 + l15][kt * 32 + quad * 8];
        #pragma unroll
        for (int nt = 0; nt < 4; ++nt) {
            const half8 wf = *(const half8*)(w2w + (kt * 16 + nt) * 512 + lo8);
            acc[0][0][nt] = __builtin_amdgcn_mfma_f32_16x16x32_f16(wf, hA0, acc[0][0][nt], 0, 0, 0);
            acc[0][1][nt] = __builtin_amdgcn_mfma_f32_16x16x32_f16(wf, hA1, acc[0][1][nt], 0, 0, 0);
            acc[1][0][nt] = __builtin_amdgcn_mfma_f32_16x16x32_f16(wf, hB0, acc[1][0][nt], 0, 0, 0);
            acc[1][1][nt] = __builtin_amdgcn_mfma_f32_16x16x32_f16(wf, hB1, acc[1][1][nt], 0, 0, 0);
        }
    }

    // ---- LN2: cvt acc->f16 pairs (acc dies), f16 stats via fdot2 ----
    half2t ones;
    ones[0] = (_Float16)1.0f;
    ones[1] = (_Float16)1.0f;
    half2t h2[2][2][4][2];   // [qq][mt][nt][pair]
    #pragma unroll
    for (int qq = 0; qq < 2; ++qq)
        #pragma unroll
        for (int mt = 0; mt < 2; ++mt)
            #pragma unroll
            for (int nt = 0; nt < 4; ++nt)
                #pragma unroll
                for (int rp = 0; rp < 2; ++rp) {
                    half2t pr;
                    pr[0] = (_Float16)acc[qq][mt][nt][2 * rp];
                    pr[1] = (_Float16)acc[qq][mt][nt][2 * rp + 1];
                    h2[qq][mt][nt][rp] = pr;
                }
    #pragma unroll
    for (int qq = 0; qq < 2; ++qq)
        #pragma unroll
        for (int mt = 0; mt < 2; ++mt) {
            float s = 0.0f, s2 = 0.0f;
            #pragma unroll
            for (int nt = 0; nt < 4; ++nt)
                #pragma unroll
                for (int rp = 0; rp < 2; ++rp) {
                    const half2t pr = h2[qq][mt][nt][rp];
                    s  = fdot2f(pr, ones, s);
                    s2 = fdot2f(pr, pr, s2);
                }
            s  += __shfl_xor(s, 16, 64);  s  += __shfl_xor(s, 32, 64);
            s2 += __shfl_xor(s2, 16, 64); s2 += __shfl_xor(s2, 32, 64);
            if (quad == 0) sred[qq][mt][l15][w] = make_float2(s, s2);
        }
    __syncthreads();   // ALL H16 B-reads done (in-place store safe) + partials
    #pragma unroll
    for (int qq = 0; qq < 2; ++qq)
        #pragma unroll
        for (int mt = 0; mt < 2; ++mt) {
            const float4 pA = *(const float4*)&sred[qq][mt][l15][0];
            const float4 pB = *(const float4*)&sred[qq][mt][l15][2];
            const float S = pA.x + pA.z + pB.x + pB.z;
            const float Q = pA.y + pA.w + pB.y + pB.w;
            const float m_ = S * (1.0f / 256.0f);
            const float var = fmaf(Q, 1.0f / 256.0f, -m_ * m_);
            mu[qq][mt] = m_;
            rs[qq][mt] = __builtin_amdgcn_rsqf(var + 1e-5f);
        }

    // ---- LN2 apply packed f16 (no activation), store into H16 ----
    half2t rsh2[2][2], nmu2[2][2];
    #pragma unroll
    for (int qq = 0; qq < 2; ++qq)
        #pragma unroll
        for (int mt = 0; mt < 2; ++mt) {
            half2t a, bpk;
            a[0] = (_Float16)rs[qq][mt];   a[1] = (_Float16)rs[qq][mt];
            bpk[0] = (_Float16)(-mu[qq][mt]); bpk[1] = (_Float16)(-mu[qq][mt]);
            rsh2[qq][mt] = a;
            nmu2[qq][mt] = bpk;
        }
    #pragma unroll
    for (int nt = 0; nt < 4; ++nt) {
        const int chb = (w * 4 + nt) * 16 + quad * 4;
        const half2t gp0 = *(const half2t*)&g2h[chb];
        const half2t gp1 = *(const half2t*)&g2h[chb + 2];
        const half2t bp0 = *(const half2t*)&be2h[chb];
        const half2t bp1 = *(const half2t*)&be2h[chb + 2];
        #pragma unroll
        for (int qq = 0; qq < 2; ++qq)
            #pragma unroll
            for (int mt = 0; mt < 2; ++mt) {
                const half2t A0 = gp0 * rsh2[qq][mt];
                const half2t A1 = gp1 * rsh2[qq][mt];
                const half2t B0 = A0 * nmu2[qq][mt] + bp0;
                const half2t B1 = A1 * nmu2[qq][mt] + bp1;
                const half2t y0 = h2[qq][mt][nt][0] * A0 + B0;
                const half2t y1 = h2[qq][mt][nt][1] * A1 + B1;
                half4v hv;
                hv[0] = y0[0]; hv[1] = y0[1]; hv[2] = y1[0]; hv[3] = y1[1];
                if (qq == 0) *(half4v*)&H16a[mt * 16 + l15][chb] = hv;
                else         *(half4v*)&H16b[mt * 16 + l15][chb] = hv;
            }
    }
    __syncthreads();

    // ---- Phase 6: packed max over 32 points, all 256 threads (2 queries) ----
    {
        const int qq = t >> 7;
        const int tt = t & 127;
        const _Float16* Hf = qq ? &H16b[0][0] : &H16a[0][0];
        half2t mx = *(const half2t*)(Hf + 2 * tt);
        #pragma unroll
        for (int r = 1; r < KN; ++r) {
            const half2t v = *(const half2t*)(Hf + r * HSTR + 2 * tt);
            mx = __builtin_elementwise_max(mx, v);
        }
        float2 o2;
        o2.x = (float)mx[0];
        o2.y = (float)mx[1];
        *(float2*)&out0[(size_t)(q0 + qq) * C + 2 * tt] = o2;
    }
}

extern "C" void kernel_launch(void* const* d_in, const int* in_sizes, int n_in,
                              void* d_out, int out_size, void* d_ws, size_t ws_size,
                              hipStream_t stream) {
    const float* xyz = (const float*)d_in[0];
    const float* pf  = (const float*)d_in[1];
    const float* ctr = (const float*)d_in[2];
    const float* W1  = (const float*)d_in[3];
    const float* b1  = (const float*)d_in[4];
    const float* g1  = (const float*)d_in[5];
    const float* be1 = (const float*)d_in[6];
    const float* W2  = (const float*)d_in[7];
    const float* b2  = (const float*)d_in[8];
    const float* g2  = (const float*)d_in[9];
    const float* be2 = (const float*)d_in[10];

    float* out = (float*)d_out;
    _Float16* wp = (_Float16*)d_ws;
    float4* xyzw = (float4*)(wp + WP_ELEMS);   // 180224 B offset, 16-aligned; +2.06 MB

    prep_kernel<<<(WP_ELEMS + XYZW_ELEMS) / 256, 256, 0, stream>>>(W1, b1, W2, xyz, wp, xyzw);
    encoder_fused<<<NQ / 2, 256, 0, stream>>>(xyzw, pf, ctr,
                                              g1, be1, b2, g2, be2,
                                              wp, wp + W1P_ELEMS,
                                              out, out + PF_ELEMS);
}

// Round 6
// 176.286 us; speedup vs baseline: 1.0303x; 1.0303x over previous
//
#include <hip/hip_runtime.h>
#include <math.h>

#define NPTS 16384
#define NPTS_PAD 16896       // +512 float4 pad per batch for scan prefetch
#define KN 32
#define C 256
#define NQ 8192              // 8 * 1024 queries
#define PF_ELEMS (NQ * C)

#define W1P_ELEMS (3 * 16 * 64 * 8)                 // 24576  (Ktiles=3, Ntiles=16)
#define W2P_ELEMS (8 * 16 * 64 * 8)                 // 65536  (Ktiles=8)
#define WP_ELEMS  (W1P_ELEMS + W2P_ELEMS)           // 90112 halves = 180224 B (16-aligned)
#define XYZW_ELEMS (8 * NPTS_PAD)                   // 135168 float4
#define HSTR 264                                    // halves per H16 row

typedef _Float16 half8 __attribute__((ext_vector_type(8)));
typedef _Float16 half4v __attribute__((ext_vector_type(4)));
typedef _Float16 half2t __attribute__((ext_vector_type(2)));
typedef float f32x4 __attribute__((ext_vector_type(4)));

__device__ __forceinline__ float exp2f_fast(float x) {
#if __has_builtin(__builtin_amdgcn_exp2f)
    return __builtin_amdgcn_exp2f(x);
#else
    return exp2f(x);
#endif
}

// tanh-approx GeLU, exp2-folded: y = x - x/(2^(x*p2L)+1), p2L = p2 * log2(e).
// 7 VALU ops (2 transcendental); max err ~3e-4 (same poly as before).
__device__ __forceinline__ float gelu_tanh(float x) {
    const float t  = x * x;
    const float p2 = fmaf(t, 0.10294324f, 2.3022083f);   // {0.07135482, 1.59576912} * log2e
    const float e  = exp2f_fast(x * p2);
    return fmaf(-x, __builtin_amdgcn_rcpf(e + 1.0f), x);
}

// ---------------------------------------------------------------------------
// Prep: pack W1 (91x256 + b1 folded at k=91, K-padded to 96) and W2 (256x256)
// into f16 fragment order; pack xyz into float4 (x,y,z,|p|^2) with the EXACT
// rounding sequence the encoder's ball query uses (bit-identical membership).
// xyzw is padded per batch to NPTS_PAD (scan prefetch overruns by <=512).
//   flat = ((kt*16 + nt)*64 + lane)*8 + j
//   k = kt*32 + (lane>>4)*8 + j ;  ch = nt*16 + (lane&15)
// ---------------------------------------------------------------------------
__global__ void prep_kernel(const float* __restrict__ W1,
                            const float* __restrict__ b1,
                            const float* __restrict__ W2,
                            const float* __restrict__ xyz,
                            _Float16* __restrict__ wp,
                            float4* __restrict__ xyzw) {
    const int idx = blockIdx.x * 256 + threadIdx.x;   // 0 .. 225279
    if (idx < 96 * 256) {
        const int k = idx >> 8, n = idx & 255;
        const float v = (k < 91) ? W1[k * 256 + n] : ((k == 91) ? b1[n] : 0.0f);
        const int kt = k >> 5, quad = (k >> 3) & 3, j = k & 7;
        const int nt = n >> 4, l15 = n & 15;
        wp[(((kt * 16 + nt) * 64) + quad * 16 + l15) * 8 + j] = (_Float16)v;
    } else if (idx < WP_ELEMS) {
        const int e = idx - 96 * 256;
        const int k = e >> 8, n = e & 255;
        const int kt = k >> 5, quad = (k >> 3) & 3, j = k & 7;
        const int nt = n >> 4, l15 = n & 15;
        wp[W1P_ELEMS + (((kt * 16 + nt) * 64) + quad * 16 + l15) * 8 + j] =
            (_Float16)W2[k * 256 + n];
    } else {
        const int e  = idx - WP_ELEMS;                // 0 .. 135167
        const int bb = e / NPTS_PAD;
        const int off = e - bb * NPTS_PAD;
        float4 v;
        if (off < NPTS) {
            const float px = xyz[((size_t)bb * NPTS + off) * 3 + 0];
            const float py = xyz[((size_t)bb * NPTS + off) * 3 + 1];
            const float pz = xyz[((size_t)bb * NPTS + off) * 3 + 2];
            const float sp = __fadd_rn(__fadd_rn(__fmul_rn(px, px), __fmul_rn(py, py)),
                                       __fmul_rn(pz, pz));
            v = make_float4(px, py, pz, sp);
        } else {
            v = make_float4(1e9f, 1e9f, 1e9f, 3e18f);  // sentinel pad (never in-ball)
        }
        xyzw[(size_t)bb * NPTS_PAD + off] = v;
    }
}

// ---------------------------------------------------------------------------
// Fused: ball-query + gather/posenc + MLP1(LN,GeLU) + MLP2(LN) + max.
// Round-19 (session R6): spill revert.
//  * R5 post-mortem: LN2 packed-f16 h2[32-reg] staging + acc[64] + bv[16]
//    blew the register budget -> scratch spills (WRITE_SIZE 12.4 -> 72 MB),
//    wall regressed despite VALUBusy 63 -> 56. Reverted LN2 to R4's f32
//    scheme (stats on f32 acc in-register, f32 apply, single f16 store).
//  * KEPT from R5 (each register-neutral): GeLU exp2-fold (9->7 ops),
//    b2 folded into GEMM2 C-init (bv loaded AFTER the LN1-store barrier to
//    minimize live range), readfirstlane-scalarized ball-query prefix sums.
//  * keeps R1-R4: 2 queries/block, saddr weight loads, packed (x,y,z,|p|^2),
//    branchless posenc, Xs/H16 overlay, fused LN epilogues, (256,4).
// No runtime-indexed private arrays (all under full unroll, const indices).
// ---------------------------------------------------------------------------
__global__ void __launch_bounds__(256, 4)
encoder_fused(const float4* __restrict__ xyzw,
              const float* __restrict__ pf,
              const float* __restrict__ ctr,
              const float* __restrict__ g1, const float* __restrict__ be1,
              const float* __restrict__ b2, const float* __restrict__ g2,
              const float* __restrict__ be2,
              const _Float16* __restrict__ w1p,
              const _Float16* __restrict__ w2p,
              float* __restrict__ out0,      // patch_feature [8192][256]
              float* __restrict__ out1) {    // neighbor idx as float [8192][32]
    const int q0 = blockIdx.x * 2;           // queries q0, q0+1 (same batch b)
    const int b = q0 >> 10;
    const int t = threadIdx.x;
    const int w = t >> 6;
    const int lane = t & 63;
    const int quad = lane >> 4;
    const int l15  = lane & 15;

    __shared__ __align__(16) unsigned char H16raw[2][KN * HSTR * 2];  // 33792
    __shared__ __align__(16) _Float16 lnph[4 * 256];                  // 2048
    __shared__ __align__(16) float2 sred[2][2][16][4];                // 2048: [qq][mt][l15][w]
    __shared__ int nbr[2][KN];                                        // 256
    __shared__ int wcnt[2][2][2][4];                                  // [par][qq][grp][warp]

    _Float16 (*H16a)[HSTR] = (_Float16(*)[HSTR])H16raw[0];
    _Float16 (*H16b)[HSTR] = (_Float16(*)[HSTR])H16raw[1];
    _Float16 (*Xs0)[104]   = (_Float16(*)[104])H16raw[0];   // OVERLAY
    _Float16 (*Xs1)[104]   = (_Float16(*)[104])H16raw[1];   // OVERLAY
    _Float16* g1h  = lnph;
    _Float16* be1h = lnph + 256;
    _Float16* g2h  = lnph + 512;
    _Float16* be2h = lnph + 768;

    lnph[t]       = (_Float16)g1[t];
    lnph[256 + t] = (_Float16)be1[t];
    lnph[512 + t] = (_Float16)g2[t];
    lnph[768 + t] = (_Float16)be2[t];

    // ---- Phase 0: shared ball query for both centers, 512 pts/iter ----
    const float4* xwb = xyzw + (size_t)b * NPTS_PAD;
    const float cxA = ctr[q0 * 3 + 0], cyA = ctr[q0 * 3 + 1], czA = ctr[q0 * 3 + 2];
    const float cxB = ctr[q0 * 3 + 3], cyB = ctr[q0 * 3 + 4], czB = ctr[q0 * 3 + 5];
    const float scA = __fadd_rn(__fadd_rn(__fmul_rn(cxA, cxA), __fmul_rn(cyA, cyA)),
                                __fmul_rn(czA, czA));
    const float scB = __fadd_rn(__fadd_rn(__fmul_rn(cxB, cxB), __fmul_rn(cyB, cyB)),
                                __fmul_rn(czB, czB));

    float4 pw0 = xwb[t];
    float4 pw1 = xwb[256 + t];
    int foundA = 0, foundB = 0;
    int par = 0;
    for (int base = 0; base < NPTS; base += 512) {
        // prefetch next iteration (pad guarantees in-bounds; unused at tail)
        const float4 nx0 = xwb[base + 512 + t];
        const float4 nx1 = xwb[base + 768 + t];

        const float dA0 = __fadd_rn(__fadd_rn(__fmul_rn(cxA, pw0.x), __fmul_rn(cyA, pw0.y)),
                                    __fmul_rn(czA, pw0.z));
        const float sA0 = __fsub_rn(__fadd_rn(scA, pw0.w), __fmul_rn(2.0f, dA0));
        const float dA1 = __fadd_rn(__fadd_rn(__fmul_rn(cxA, pw1.x), __fmul_rn(cyA, pw1.y)),
                                    __fmul_rn(czA, pw1.z));
        const float sA1 = __fsub_rn(__fadd_rn(scA, pw1.w), __fmul_rn(2.0f, dA1));
        const float dB0 = __fadd_rn(__fadd_rn(__fmul_rn(cxB, pw0.x), __fmul_rn(cyB, pw0.y)),
                                    __fmul_rn(czB, pw0.z));
        const float sB0 = __fsub_rn(__fadd_rn(scB, pw0.w), __fmul_rn(2.0f, dB0));
        const float dB1 = __fadd_rn(__fadd_rn(__fmul_rn(cxB, pw1.x), __fmul_rn(cyB, pw1.y)),
                                    __fmul_rn(czB, pw1.z));
        const float sB1 = __fsub_rn(__fadd_rn(scB, pw1.w), __fmul_rn(2.0f, dB1));
        const bool iA0 = (sA0 <= 0.0625f);
        const bool iA1 = (sA1 <= 0.0625f);
        const bool iB0 = (sB0 <= 0.0625f);
        const bool iB1 = (sB1 <= 0.0625f);

        const unsigned long long mA0 = __ballot(iA0);
        const unsigned long long mA1 = __ballot(iA1);
        const unsigned long long mB0 = __ballot(iB0);
        const unsigned long long mB1 = __ballot(iB1);
        if (lane == 0) {
            wcnt[par][0][0][w] = (int)__popcll(mA0);
            wcnt[par][0][1][w] = (int)__popcll(mA1);
            wcnt[par][1][0][w] = (int)__popcll(mB0);
            wcnt[par][1][1][w] = (int)__popcll(mB1);
        }
        __syncthreads();
        const unsigned long long lmask = (1ull << lane) - 1ull;
        {   // query A compaction (counts are wave-uniform -> SALU via rfl)
            const int c00 = __builtin_amdgcn_readfirstlane(wcnt[par][0][0][0]);
            const int c01 = __builtin_amdgcn_readfirstlane(wcnt[par][0][0][1]);
            const int c02 = __builtin_amdgcn_readfirstlane(wcnt[par][0][0][2]);
            const int c03 = __builtin_amdgcn_readfirstlane(wcnt[par][0][0][3]);
            const int c10 = __builtin_amdgcn_readfirstlane(wcnt[par][0][1][0]);
            const int c11 = __builtin_amdgcn_readfirstlane(wcnt[par][0][1][1]);
            const int c12 = __builtin_amdgcn_readfirstlane(wcnt[par][0][1][2]);
            const int c13 = __builtin_amdgcn_readfirstlane(wcnt[par][0][1][3]);
            int pre0 = foundA;
            if (w > 0) pre0 += c00;
            if (w > 1) pre0 += c01;
            if (w > 2) pre0 += c02;
            const int C0 = c00 + c01 + c02 + c03;
            int pre1 = foundA + C0;
            if (w > 0) pre1 += c10;
            if (w > 1) pre1 += c11;
            if (w > 2) pre1 += c12;
            const int pos0 = pre0 + (int)__popcll(mA0 & lmask);
            const int pos1 = pre1 + (int)__popcll(mA1 & lmask);
            if (iA0 && pos0 < KN) nbr[0][pos0] = base + t;
            if (iA1 && pos1 < KN) nbr[0][pos1] = base + 256 + t;
            foundA += C0 + c10 + c11 + c12 + c13;   // block-uniform
        }
        {   // query B compaction
            const int c00 = __builtin_amdgcn_readfirstlane(wcnt[par][1][0][0]);
            const int c01 = __builtin_amdgcn_readfirstlane(wcnt[par][1][0][1]);
            const int c02 = __builtin_amdgcn_readfirstlane(wcnt[par][1][0][2]);
            const int c03 = __builtin_amdgcn_readfirstlane(wcnt[par][1][0][3]);
            const int c10 = __builtin_amdgcn_readfirstlane(wcnt[par][1][1][0]);
            const int c11 = __builtin_amdgcn_readfirstlane(wcnt[par][1][1][1]);
            const int c12 = __builtin_amdgcn_readfirstlane(wcnt[par][1][1][2]);
            const int c13 = __builtin_amdgcn_readfirstlane(wcnt[par][1][1][3]);
            int pre0 = foundB;
            if (w > 0) pre0 += c00;
            if (w > 1) pre0 += c01;
            if (w > 2) pre0 += c02;
            const int C0 = c00 + c01 + c02 + c03;
            int pre1 = foundB + C0;
            if (w > 0) pre1 += c10;
            if (w > 1) pre1 += c11;
            if (w > 2) pre1 += c12;
            const int pos0 = pre0 + (int)__popcll(mB0 & lmask);
            const int pos1 = pre1 + (int)__popcll(mB1 & lmask);
            if (iB0 && pos0 < KN) nbr[1][pos0] = base + t;
            if (iB1 && pos1 < KN) nbr[1][pos1] = base + 256 + t;
            foundB += C0 + c10 + c11 + c12 + c13;   // block-uniform
        }
        par ^= 1;
        if (foundA >= KN && foundB >= KN) break;
        pw0 = nx0;
        pw1 = nx1;
    }
    __syncthreads();                  // nbr visible to all
    const int cntA = (foundA < KN) ? foundA : KN;
    const int cntB = (foundB < KN) ? foundB : KN;
    const int fstA = (cntA > 0) ? nbr[0][0] : NPTS;
    const int fstB = (cntB > 0) ? nbr[1][0] : NPTS;

    if (t < 2 * KN) {
        const int qq = t >> 5, i = t & 31;
        const int cnt = qq ? cntB : cntA;
        const int fst = qq ? fstB : fstA;
        out1[(size_t)(q0 + qq) * KN + i] = (float)((i < cnt) ? nbr[qq][i] : fst);
    }

    // ---- Phase 1: gather + rel + posenc into XsQ (k=91 is 1.0 for b1) ----
    #pragma unroll
    for (int qq = 0; qq < 2; ++qq) {
        const int k  = t >> 3;
        const int tc = t & 7;
        const int cnt = qq ? cntB : cntA;
        const int fst = qq ? fstB : fstA;
        const float ccx = qq ? cxB : cxA;
        const float ccy = qq ? cyB : cyA;
        const float ccz = qq ? czB : czA;
        const int nidx = (k < cnt) ? nbr[qq][k] : fst;
        const int n = (nidx < NPTS) ? nidx : NPTS - 1;   // JAX OOB gather clamp
        const float4 pw = xwb[n];
        const float rx = pw.x - ccx;
        const float ry = pw.y - ccy;
        const float rz = pw.z - ccz;
        const float* pfr = pf + ((size_t)b * NPTS + n) * 64;

        const float4 f0 = *(const float4*)(pfr + tc * 8);
        const float4 f1 = *(const float4*)(pfr + tc * 8 + 4);
        half8 hv;
        hv[0] = (_Float16)f0.x; hv[1] = (_Float16)f0.y;
        hv[2] = (_Float16)f0.z; hv[3] = (_Float16)f0.w;
        hv[4] = (_Float16)f1.x; hv[5] = (_Float16)f1.y;
        hv[6] = (_Float16)f1.z; hv[7] = (_Float16)f1.w;
        if (qq == 0) *(half8*)&Xs0[k][tc * 8] = hv;
        else         *(half8*)&Xs1[k][tc * 8] = hv;

        half4v ov;
        #pragma unroll
        for (int j = 0; j < 4; ++j) {
            const int cm = tc * 4 + j;          // 0..31
            const int jj = cm - 3;
            const int d  = jj >> 3;
            const int mm = jj & 7;
            const float rsel = (d == 0) ? rx : ((d == 1) ? ry : rz);
            const float f2 = __int_as_float(0x3E22F983 + ((mm & 3) << 23));
            const float arg = fmaf(rsel, f2, (mm >= 4) ? 0.25f : 0.0f);
#if __has_builtin(__builtin_amdgcn_sinf)
            const float sv = __builtin_amdgcn_sinf(arg);
#else
            const float sv = __sinf(arg * 6.2831853071795864f);
#endif
            float v = (cm < 3) ? ((cm == 0) ? rx : ((cm == 1) ? ry : rz)) : sv;
            v = (cm == 27) ? 1.0f : ((cm > 27) ? 0.0f : v);
            ov[j] = (_Float16)v;
        }
        if (qq == 0) *(half4v*)&Xs0[k][64 + tc * 4] = ov;
        else         *(half4v*)&Xs1[k][64 + tc * 4] = ov;
    }
    __syncthreads();

    f32x4 acc[2][2][4];   // [qq][mt][nt]; lane: ch=(w*4+nt)*16+quad*4+r, pt=mt*16+l15

    // uniform (SGPR) weight bases + per-lane voffset -> saddr-form loads
    const int wu = __builtin_amdgcn_readfirstlane(w);
    const _Float16* __restrict__ w1w = w1p + (size_t)(wu * 4) * 512;
    const _Float16* __restrict__ w2w = w2p + (size_t)(wu * 4) * 512;
    const int lo8 = lane * 8;

    // ---- GEMM1: W1^T as A, Xs{0,1} as B -> acc (b1 via folded row) ----
    #pragma unroll
    for (int qq = 0; qq < 2; ++qq)
        #pragma unroll
        for (int mt = 0; mt < 2; ++mt)
            #pragma unroll
            for (int nt = 0; nt < 4; ++nt)
                acc[qq][mt][nt] = (f32x4){0.f, 0.f, 0.f, 0.f};

    #pragma unroll
    for (int kt = 0; kt < 3; ++kt) {
        const half8 xA0 = *(const half8*)&Xs0[l15][kt * 32 + quad * 8];
        const half8 xA1 = *(const half8*)&Xs0[16 + l15][kt * 32 + quad * 8];
        const half8 xB0 = *(const half8*)&Xs1[l15][kt * 32 + quad * 8];
        const half8 xB1 = *(const half8*)&Xs1[16 + l15][kt * 32 + quad * 8];
        #pragma unroll
        for (int nt = 0; nt < 4; ++nt) {
            const half8 wf = *(const half8*)(w1w + (kt * 16 + nt) * 512 + lo8);
            acc[0][0][nt] = __builtin_amdgcn_mfma_f32_16x16x32_f16(wf, xA0, acc[0][0][nt], 0, 0, 0);
            acc[0][1][nt] = __builtin_amdgcn_mfma_f32_16x16x32_f16(wf, xA1, acc[0][1][nt], 0, 0, 0);
            acc[1][0][nt] = __builtin_amdgcn_mfma_f32_16x16x32_f16(wf, xB0, acc[1][0][nt], 0, 0, 0);
            acc[1][1][nt] = __builtin_amdgcn_mfma_f32_16x16x32_f16(wf, xB1, acc[1][1][nt], 0, 0, 0);
        }
    }

    // ---- LN1 stats on f32 accs (in-register + quad shfl + cross-warp LDS) ----
    float mu[2][2], rs[2][2];
    #pragma unroll
    for (int qq = 0; qq < 2; ++qq)
        #pragma unroll
        for (int mt = 0; mt < 2; ++mt) {
            float s = 0.0f, s2 = 0.0f;
            #pragma unroll
            for (int nt = 0; nt < 4; ++nt)
                #pragma unroll
                for (int r = 0; r < 4; ++r) {
                    const float v = acc[qq][mt][nt][r];
                    s += v;
                    s2 = fmaf(v, v, s2);
                }
            s  += __shfl_xor(s, 16, 64);  s  += __shfl_xor(s, 32, 64);
            s2 += __shfl_xor(s2, 16, 64); s2 += __shfl_xor(s2, 32, 64);
            if (quad == 0) sred[qq][mt][l15][w] = make_float2(s, s2);
        }
    __syncthreads();   // overlay fence (Xs reads done) + sred partials visible
    #pragma unroll
    for (int qq = 0; qq < 2; ++qq)
        #pragma unroll
        for (int mt = 0; mt < 2; ++mt) {
            const float4 pA = *(const float4*)&sred[qq][mt][l15][0];
            const float4 pB = *(const float4*)&sred[qq][mt][l15][2];
            const float S = pA.x + pA.z + pB.x + pB.z;
            const float Q = pA.y + pA.w + pB.y + pB.w;
            const float m_ = S * (1.0f / 256.0f);
            const float var = fmaf(Q, 1.0f / 256.0f, -m_ * m_);
            mu[qq][mt] = m_;
            rs[qq][mt] = __builtin_amdgcn_rsqf(var + 1e-5f);
        }

    // ---- LN1 apply + GeLU in f32, single f16 store into H16 ----
    #pragma unroll
    for (int nt = 0; nt < 4; ++nt) {
        const int chb = (w * 4 + nt) * 16 + quad * 4;
        const half4v g4h  = *(const half4v*)&g1h[chb];
        const half4v be4h = *(const half4v*)&be1h[chb];
        #pragma unroll
        for (int qq = 0; qq < 2; ++qq)
            #pragma unroll
            for (int mt = 0; mt < 2; ++mt) {
                half4v h;
                #pragma unroll
                for (int r = 0; r < 4; ++r) {
                    const float A = (float)g4h[r] * rs[qq][mt];
                    const float y = fmaf(acc[qq][mt][nt][r] - mu[qq][mt], A, (float)be4h[r]);
                    h[r] = (_Float16)gelu_tanh(y);
                }
                if (qq == 0) *(half4v*)&H16a[mt * 16 + l15][chb] = h;
                else         *(half4v*)&H16b[mt * 16 + l15][chb] = h;
            }
    }
    __syncthreads();   // H16 ready for GEMM2 B-reads

    // b2 fragments for GEMM2 C-init (short live range: load here, die at init)
    f32x4 bv[4];
    #pragma unroll
    for (int nt = 0; nt < 4; ++nt)
        bv[nt] = *(const f32x4*)&b2[(w * 4 + nt) * 16 + quad * 4];

    // ---- GEMM2: W2^T as A, H{a,b} as B; C-init = b2 (fold) ----
    #pragma unroll
    for (int qq = 0; qq < 2; ++qq)
        #pragma unroll
        for (int mt = 0; mt < 2; ++mt)
            #pragma unroll
            for (int nt = 0; nt < 4; ++nt)
                acc[qq][mt][nt] = bv[nt];

    #pragma unroll
    for (int kt = 0; kt < 8; ++kt) {
        const half8 hA0 = *(const half8*)&H16a[l15][kt * 32 + quad * 8];
        const half8 hA1 = *(const half8*)&H16a[16 + l15][kt * 32 + quad * 8];
        const half8 hB0 = *(const half8*)&H16b[l15][kt * 32 + quad * 8];
        const half8 hB1 = *(const half8*)&H16b[16 + l15][kt * 32 + quad * 8];
        #pragma unroll
        for (int nt = 0; nt < 4; ++nt) {
            const half8 wf = *(const half8*)(w2w + (kt * 16 + nt) * 512 + lo8);
            acc[0][0][nt] = __builtin_amdgcn_mfma_f32_16x16x32_f16(wf, hA0, acc[0][0][nt], 0, 0, 0);
            acc[0][1][nt] = __builtin_amdgcn_mfma_f32_16x16x32_f16(wf, hA1, acc[0][1][nt], 0, 0, 0);
            acc[1][0][nt] = __builtin_amdgcn_mfma_f32_16x16x32_f16(wf, hB0, acc[1][0][nt], 0, 0, 0);
            acc[1][1][nt] = __builtin_amdgcn_mfma_f32_16x16x32_f16(wf, hB1, acc[1][1][nt], 0, 0, 0);
        }
    }

    // ---- LN2 stats on f32 accs (b2 already folded in) ----
    #pragma unroll
    for (int qq = 0; qq < 2; ++qq)
        #pragma unroll
        for (int mt = 0; mt < 2; ++mt) {
            float s = 0.0f, s2 = 0.0f;
            #pragma unroll
            for (int nt = 0; nt < 4; ++nt)
                #pragma unroll
                for (int r = 0; r < 4; ++r) {
                    const float v = acc[qq][mt][nt][r];
                    s += v;
                    s2 = fmaf(v, v, s2);
                }
            s  += __shfl_xor(s, 16, 64);  s  += __shfl_xor(s, 32, 64);
            s2 += __shfl_xor(s2, 16, 64); s2 += __shfl_xor(s2, 32, 64);
            if (quad == 0) sred[qq][mt][l15][w] = make_float2(s, s2);
        }
    __syncthreads();   // ALL H16 B-reads done (in-place store safe) + partials
    #pragma unroll
    for (int qq = 0; qq < 2; ++qq)
        #pragma unroll
        for (int mt = 0; mt < 2; ++mt) {
            const float4 pA = *(const float4*)&sred[qq][mt][l15][0];
            const float4 pB = *(const float4*)&sred[qq][mt][l15][2];
            const float S = pA.x + pA.z + pB.x + pB.z;
            const float Q = pA.y + pA.w + pB.y + pB.w;
            const float m_ = S * (1.0f / 256.0f);
            const float var = fmaf(Q, 1.0f / 256.0f, -m_ * m_);
            mu[qq][mt] = m_;
            rs[qq][mt] = __builtin_amdgcn_rsqf(var + 1e-5f);
        }

    // ---- LN2 apply (no activation), f16 store into H16 ----
    #pragma unroll
    for (int nt = 0; nt < 4; ++nt) {
        const int chb = (w * 4 + nt) * 16 + quad * 4;
        const half4v g4h  = *(const half4v*)&g2h[chb];
        const half4v be4h = *(const half4v*)&be2h[chb];
        #pragma unroll
        for (int qq = 0; qq < 2; ++qq)
            #pragma unroll
            for (int mt = 0; mt < 2; ++mt) {
                half4v h;
                #pragma unroll
                for (int r = 0; r < 4; ++r) {
                    const float A = (float)g4h[r] * rs[qq][mt];
                    h[r] = (_Float16)fmaf(acc[qq][mt][nt][r] - mu[qq][mt], A, (float)be4h[r]);
                }
                if (qq == 0) *(half4v*)&H16a[mt * 16 + l15][chb] = h;
                else         *(half4v*)&H16b[mt * 16 + l15][chb] = h;
            }
    }
    __syncthreads();

    // ---- Phase 6: packed max over 32 points, all 256 threads (2 queries) ----
    {
        const int qq = t >> 7;
        const int tt = t & 127;
        const _Float16* Hf = qq ? &H16b[0][0] : &H16a[0][0];
        half2t mx = *(const half2t*)(Hf + 2 * tt);
        #pragma unroll
        for (int r = 1; r < KN; ++r) {
            const half2t v = *(const half2t*)(Hf + r * HSTR + 2 * tt);
            mx = __builtin_elementwise_max(mx, v);
        }
        float2 o2;
        o2.x = (float)mx[0];
        o2.y = (float)mx[1];
        *(float2*)&out0[(size_t)(q0 + qq) * C + 2 * tt] = o2;
    }
}

extern "C" void kernel_launch(void* const* d_in, const int* in_sizes, int n_in,
                              void* d_out, int out_size, void* d_ws, size_t ws_size,
                              hipStream_t stream) {
    const float* xyz = (const float*)d_in[0];
    const float* pf  = (const float*)d_in[1];
    const float* ctr = (const float*)d_in[2];
    const float* W1  = (const float*)d_in[3];
    const float* b1  = (const float*)d_in[4];
    const float* g1  = (const float*)d_in[5];
    const float* be1 = (const float*)d_in[6];
    const float* W2  = (const float*)d_in[7];
    const float* b2  = (const float*)d_in[8];
    const float* g2  = (const float*)d_in[9];
    const float* be2 = (const float*)d_in[10];

    float* out = (float*)d_out;
    _Float16* wp = (_Float16*)d_ws;
    float4* xyzw = (float4*)(wp + WP_ELEMS);   // 180224 B offset, 16-aligned; +2.06 MB

    prep_kernel<<<(WP_ELEMS + XYZW_ELEMS) / 256, 256, 0, stream>>>(W1, b1, W2, xyz, wp, xyzw);
    encoder_fused<<<NQ / 2, 256, 0, stream>>>(xyzw, pf, ctr,
                                              g1, be1, b2, g2, be2,
                                              wp, wp + W1P_ELEMS,
                                              out, out + PF_ELEMS);
}

// Round 7
// 174.625 us; speedup vs baseline: 1.0401x; 1.0095x over previous
//
#include <hip/hip_runtime.h>
#include <math.h>

#define NPTS 16384
#define NPTS_PAD 16896       // +512 float4 pad per batch for scan prefetch
#define KN 32
#define C 256
#define NQ 8192              // 8 * 1024 queries
#define PF_ELEMS (NQ * C)

#define W1P_ELEMS (3 * 16 * 64 * 8)                 // 24576  (Ktiles=3, Ntiles=16)
#define W2P_ELEMS (8 * 16 * 64 * 8)                 // 65536  (Ktiles=8)
#define WP_ELEMS  (W1P_ELEMS + W2P_ELEMS)           // 90112 halves = 180224 B (16-aligned)
#define XYZW_ELEMS (8 * NPTS_PAD)                   // 135168 float4
#define HSTR 264                                    // halves per H16 row

typedef _Float16 half8 __attribute__((ext_vector_type(8)));
typedef _Float16 half4v __attribute__((ext_vector_type(4)));
typedef _Float16 half2t __attribute__((ext_vector_type(2)));
typedef float f32x4 __attribute__((ext_vector_type(4)));
typedef float f32x2 __attribute__((ext_vector_type(2)));

__device__ __forceinline__ float exp2f_fast(float x) {
#if __has_builtin(__builtin_amdgcn_exp2f)
    return __builtin_amdgcn_exp2f(x);
#else
    return exp2f(x);
#endif
}

// packed dual-f32 fma (CDNA v_pk_fma_f32)
__device__ __forceinline__ f32x2 pkfma(f32x2 a, f32x2 b, f32x2 c) {
#if __has_builtin(__builtin_elementwise_fma)
    return __builtin_elementwise_fma(a, b, c);
#else
    f32x2 r;
    r.x = fmaf(a.x, b.x, c.x);
    r.y = fmaf(a.y, b.y, c.y);
    return r;
#endif
}

// tanh-approx GeLU on 2 elements: poly part packed (v_pk_*), trans scalar.
// Per-element math identical to the proven scalar version (exp2-folded).
__device__ __forceinline__ f32x2 gelu2(f32x2 y) {
    const f32x2 c1 = {0.10294324f, 0.10294324f};   // 0.07135482 * log2e
    const f32x2 c0 = {2.3022083f, 2.3022083f};     // 1.59576912 * log2e
    const f32x2 t = y * y;
    const f32x2 p = pkfma(t, c1, c0);
    const f32x2 z = y * p;
    const float e0 = exp2f_fast(z.x);
    const float e1 = exp2f_fast(z.y);
    const float r0 = __builtin_amdgcn_rcpf(e0 + 1.0f);
    const float r1 = __builtin_amdgcn_rcpf(e1 + 1.0f);
    f32x2 o;
    o.x = fmaf(-y.x, r0, y.x);
    o.y = fmaf(-y.y, r1, y.y);
    return o;
}

// ---------------------------------------------------------------------------
// Prep: pack W1 (91x256 + b1 folded at k=91, K-padded to 96) and W2 (256x256)
// into f16 fragment order; pack xyz into float4 (x,y,z,|p|^2) with the EXACT
// rounding sequence the encoder's ball query uses (bit-identical membership).
// xyzw is padded per batch to NPTS_PAD (scan prefetch overruns by <=512).
//   flat = ((kt*16 + nt)*64 + lane)*8 + j
//   k = kt*32 + (lane>>4)*8 + j ;  ch = nt*16 + (lane&15)
// ---------------------------------------------------------------------------
__global__ void prep_kernel(const float* __restrict__ W1,
                            const float* __restrict__ b1,
                            const float* __restrict__ W2,
                            const float* __restrict__ xyz,
                            _Float16* __restrict__ wp,
                            float4* __restrict__ xyzw) {
    const int idx = blockIdx.x * 256 + threadIdx.x;   // 0 .. 225279
    if (idx < 96 * 256) {
        const int k = idx >> 8, n = idx & 255;
        const float v = (k < 91) ? W1[k * 256 + n] : ((k == 91) ? b1[n] : 0.0f);
        const int kt = k >> 5, quad = (k >> 3) & 3, j = k & 7;
        const int nt = n >> 4, l15 = n & 15;
        wp[(((kt * 16 + nt) * 64) + quad * 16 + l15) * 8 + j] = (_Float16)v;
    } else if (idx < WP_ELEMS) {
        const int e = idx - 96 * 256;
        const int k = e >> 8, n = e & 255;
        const int kt = k >> 5, quad = (k >> 3) & 3, j = k & 7;
        const int nt = n >> 4, l15 = n & 15;
        wp[W1P_ELEMS + (((kt * 16 + nt) * 64) + quad * 16 + l15) * 8 + j] =
            (_Float16)W2[k * 256 + n];
    } else {
        const int e  = idx - WP_ELEMS;                // 0 .. 135167
        const int bb = e / NPTS_PAD;
        const int off = e - bb * NPTS_PAD;
        float4 v;
        if (off < NPTS) {
            const float px = xyz[((size_t)bb * NPTS + off) * 3 + 0];
            const float py = xyz[((size_t)bb * NPTS + off) * 3 + 1];
            const float pz = xyz[((size_t)bb * NPTS + off) * 3 + 2];
            const float sp = __fadd_rn(__fadd_rn(__fmul_rn(px, px), __fmul_rn(py, py)),
                                       __fmul_rn(pz, pz));
            v = make_float4(px, py, pz, sp);
        } else {
            v = make_float4(1e9f, 1e9f, 1e9f, 3e18f);  // sentinel pad (never in-ball)
        }
        xyzw[(size_t)bb * NPTS_PAD + off] = v;
    }
}

// ---------------------------------------------------------------------------
// Fused: ball-query + gather/posenc + MLP1(LN,GeLU) + MLP2(LN) + max.
// Round-20 (session R7): packed-f32 (VOP3P) epilogues.
//  * R6 post-mortem: issue-bound (MFMA 21 + VALU 60 = 81%); epilogue is the
//    largest audited VALU block and runs scalar f32. CDNA4 has full-rate
//    v_pk_{fma,mul,add}_f32 selected from <2 x float> IR -> rewrite LN stats,
//    LN applies, GeLU poly on f32x2 halves of acc (~2x fewer instrs there;
//    trans stay scalar). Per-element math identical (GeLU) or proven-adjacent
//    (A/B LN form = baseline round-13; pairwise stats = R0-R2 fdot2 scheme).
//  * LN gamma/beta tables now stored in LDS as f32 (no f16 roundtrip: -36
//    cvt/wave; LDS 38400 -> ~40448, still 4 blocks/CU).
//  * keeps R1-R6: 2 queries/block, saddr weight loads, packed (x,y,z,|p|^2),
//    branchless posenc, Xs/H16 overlay, GeLU exp2-fold, b2->C-init fold,
//    SALU prefix sums, (256,4).
// No runtime-indexed private arrays (all under full unroll, const indices).
// ---------------------------------------------------------------------------
__global__ void __launch_bounds__(256, 4)
encoder_fused(const float4* __restrict__ xyzw,
              const float* __restrict__ pf,
              const float* __restrict__ ctr,
              const float* __restrict__ g1, const float* __restrict__ be1,
              const float* __restrict__ b2, const float* __restrict__ g2,
              const float* __restrict__ be2,
              const _Float16* __restrict__ w1p,
              const _Float16* __restrict__ w2p,
              float* __restrict__ out0,      // patch_feature [8192][256]
              float* __restrict__ out1) {    // neighbor idx as float [8192][32]
    const int q0 = blockIdx.x * 2;           // queries q0, q0+1 (same batch b)
    const int b = q0 >> 10;
    const int t = threadIdx.x;
    const int w = t >> 6;
    const int lane = t & 63;
    const int quad = lane >> 4;
    const int l15  = lane & 15;

    __shared__ __align__(16) unsigned char H16raw[2][KN * HSTR * 2];  // 33792
    __shared__ __align__(16) float lnpf[4 * 256];                     // 4096: g1,be1,g2,be2 (f32)
    __shared__ __align__(16) float2 sred[2][2][16][4];                // 2048: [qq][mt][l15][w]
    __shared__ int nbr[2][KN];                                        // 256
    __shared__ int wcnt[2][2][2][4];                                  // [par][qq][grp][warp]

    _Float16 (*H16a)[HSTR] = (_Float16(*)[HSTR])H16raw[0];
    _Float16 (*H16b)[HSTR] = (_Float16(*)[HSTR])H16raw[1];
    _Float16 (*Xs0)[104]   = (_Float16(*)[104])H16raw[0];   // OVERLAY
    _Float16 (*Xs1)[104]   = (_Float16(*)[104])H16raw[1];   // OVERLAY
    float* g1f  = lnpf;
    float* be1f = lnpf + 256;
    float* g2f  = lnpf + 512;
    float* be2f = lnpf + 768;

    lnpf[t]       = g1[t];
    lnpf[256 + t] = be1[t];
    lnpf[512 + t] = g2[t];
    lnpf[768 + t] = be2[t];

    // ---- Phase 0: shared ball query for both centers, 512 pts/iter ----
    const float4* xwb = xyzw + (size_t)b * NPTS_PAD;
    const float cxA = ctr[q0 * 3 + 0], cyA = ctr[q0 * 3 + 1], czA = ctr[q0 * 3 + 2];
    const float cxB = ctr[q0 * 3 + 3], cyB = ctr[q0 * 3 + 4], czB = ctr[q0 * 3 + 5];
    const float scA = __fadd_rn(__fadd_rn(__fmul_rn(cxA, cxA), __fmul_rn(cyA, cyA)),
                                __fmul_rn(czA, czA));
    const float scB = __fadd_rn(__fadd_rn(__fmul_rn(cxB, cxB), __fmul_rn(cyB, cyB)),
                                __fmul_rn(czB, czB));

    float4 pw0 = xwb[t];
    float4 pw1 = xwb[256 + t];
    int foundA = 0, foundB = 0;
    int par = 0;
    for (int base = 0; base < NPTS; base += 512) {
        // prefetch next iteration (pad guarantees in-bounds; unused at tail)
        const float4 nx0 = xwb[base + 512 + t];
        const float4 nx1 = xwb[base + 768 + t];

        const float dA0 = __fadd_rn(__fadd_rn(__fmul_rn(cxA, pw0.x), __fmul_rn(cyA, pw0.y)),
                                    __fmul_rn(czA, pw0.z));
        const float sA0 = __fsub_rn(__fadd_rn(scA, pw0.w), __fmul_rn(2.0f, dA0));
        const float dA1 = __fadd_rn(__fadd_rn(__fmul_rn(cxA, pw1.x), __fmul_rn(cyA, pw1.y)),
                                    __fmul_rn(czA, pw1.z));
        const float sA1 = __fsub_rn(__fadd_rn(scA, pw1.w), __fmul_rn(2.0f, dA1));
        const float dB0 = __fadd_rn(__fadd_rn(__fmul_rn(cxB, pw0.x), __fmul_rn(cyB, pw0.y)),
                                    __fmul_rn(czB, pw0.z));
        const float sB0 = __fsub_rn(__fadd_rn(scB, pw0.w), __fmul_rn(2.0f, dB0));
        const float dB1 = __fadd_rn(__fadd_rn(__fmul_rn(cxB, pw1.x), __fmul_rn(cyB, pw1.y)),
                                    __fmul_rn(czB, pw1.z));
        const float sB1 = __fsub_rn(__fadd_rn(scB, pw1.w), __fmul_rn(2.0f, dB1));
        const bool iA0 = (sA0 <= 0.0625f);
        const bool iA1 = (sA1 <= 0.0625f);
        const bool iB0 = (sB0 <= 0.0625f);
        const bool iB1 = (sB1 <= 0.0625f);

        const unsigned long long mA0 = __ballot(iA0);
        const unsigned long long mA1 = __ballot(iA1);
        const unsigned long long mB0 = __ballot(iB0);
        const unsigned long long mB1 = __ballot(iB1);
        if (lane == 0) {
            wcnt[par][0][0][w] = (int)__popcll(mA0);
            wcnt[par][0][1][w] = (int)__popcll(mA1);
            wcnt[par][1][0][w] = (int)__popcll(mB0);
            wcnt[par][1][1][w] = (int)__popcll(mB1);
        }
        __syncthreads();
        const unsigned long long lmask = (1ull << lane) - 1ull;
        {   // query A compaction (counts are wave-uniform -> SALU via rfl)
            const int c00 = __builtin_amdgcn_readfirstlane(wcnt[par][0][0][0]);
            const int c01 = __builtin_amdgcn_readfirstlane(wcnt[par][0][0][1]);
            const int c02 = __builtin_amdgcn_readfirstlane(wcnt[par][0][0][2]);
            const int c03 = __builtin_amdgcn_readfirstlane(wcnt[par][0][0][3]);
            const int c10 = __builtin_amdgcn_readfirstlane(wcnt[par][0][1][0]);
            const int c11 = __builtin_amdgcn_readfirstlane(wcnt[par][0][1][1]);
            const int c12 = __builtin_amdgcn_readfirstlane(wcnt[par][0][1][2]);
            const int c13 = __builtin_amdgcn_readfirstlane(wcnt[par][0][1][3]);
            int pre0 = foundA;
            if (w > 0) pre0 += c00;
            if (w > 1) pre0 += c01;
            if (w > 2) pre0 += c02;
            const int C0 = c00 + c01 + c02 + c03;
            int pre1 = foundA + C0;
            if (w > 0) pre1 += c10;
            if (w > 1) pre1 += c11;
            if (w > 2) pre1 += c12;
            const int pos0 = pre0 + (int)__popcll(mA0 & lmask);
            const int pos1 = pre1 + (int)__popcll(mA1 & lmask);
            if (iA0 && pos0 < KN) nbr[0][pos0] = base + t;
            if (iA1 && pos1 < KN) nbr[0][pos1] = base + 256 + t;
            foundA += C0 + c10 + c11 + c12 + c13;   // block-uniform
        }
        {   // query B compaction
            const int c00 = __builtin_amdgcn_readfirstlane(wcnt[par][1][0][0]);
            const int c01 = __builtin_amdgcn_readfirstlane(wcnt[par][1][0][1]);
            const int c02 = __builtin_amdgcn_readfirstlane(wcnt[par][1][0][2]);
            const int c03 = __builtin_amdgcn_readfirstlane(wcnt[par][1][0][3]);
            const int c10 = __builtin_amdgcn_readfirstlane(wcnt[par][1][1][0]);
            const int c11 = __builtin_amdgcn_readfirstlane(wcnt[par][1][1][1]);
            const int c12 = __builtin_amdgcn_readfirstlane(wcnt[par][1][1][2]);
            const int c13 = __builtin_amdgcn_readfirstlane(wcnt[par][1][1][3]);
            int pre0 = foundB;
            if (w > 0) pre0 += c00;
            if (w > 1) pre0 += c01;
            if (w > 2) pre0 += c02;
            const int C0 = c00 + c01 + c02 + c03;
            int pre1 = foundB + C0;
            if (w > 0) pre1 += c10;
            if (w > 1) pre1 += c11;
            if (w > 2) pre1 += c12;
            const int pos0 = pre0 + (int)__popcll(mB0 & lmask);
            const int pos1 = pre1 + (int)__popcll(mB1 & lmask);
            if (iB0 && pos0 < KN) nbr[1][pos0] = base + t;
            if (iB1 && pos1 < KN) nbr[1][pos1] = base + 256 + t;
            foundB += C0 + c10 + c11 + c12 + c13;   // block-uniform
        }
        par ^= 1;
        if (foundA >= KN && foundB >= KN) break;
        pw0 = nx0;
        pw1 = nx1;
    }
    __syncthreads();                  // nbr visible to all
    const int cntA = (foundA < KN) ? foundA : KN;
    const int cntB = (foundB < KN) ? foundB : KN;
    const int fstA = (cntA > 0) ? nbr[0][0] : NPTS;
    const int fstB = (cntB > 0) ? nbr[1][0] : NPTS;

    if (t < 2 * KN) {
        const int qq = t >> 5, i = t & 31;
        const int cnt = qq ? cntB : cntA;
        const int fst = qq ? fstB : fstA;
        out1[(size_t)(q0 + qq) * KN + i] = (float)((i < cnt) ? nbr[qq][i] : fst);
    }

    // ---- Phase 1: gather + rel + posenc into XsQ (k=91 is 1.0 for b1) ----
    #pragma unroll
    for (int qq = 0; qq < 2; ++qq) {
        const int k  = t >> 3;
        const int tc = t & 7;
        const int cnt = qq ? cntB : cntA;
        const int fst = qq ? fstB : fstA;
        const float ccx = qq ? cxB : cxA;
        const float ccy = qq ? cyB : cyA;
        const float ccz = qq ? czB : czA;
        const int nidx = (k < cnt) ? nbr[qq][k] : fst;
        const int n = (nidx < NPTS) ? nidx : NPTS - 1;   // JAX OOB gather clamp
        const float4 pw = xwb[n];
        const float rx = pw.x - ccx;
        const float ry = pw.y - ccy;
        const float rz = pw.z - ccz;
        const float* pfr = pf + ((size_t)b * NPTS + n) * 64;

        const float4 f0 = *(const float4*)(pfr + tc * 8);
        const float4 f1 = *(const float4*)(pfr + tc * 8 + 4);
        half8 hv;
        hv[0] = (_Float16)f0.x; hv[1] = (_Float16)f0.y;
        hv[2] = (_Float16)f0.z; hv[3] = (_Float16)f0.w;
        hv[4] = (_Float16)f1.x; hv[5] = (_Float16)f1.y;
        hv[6] = (_Float16)f1.z; hv[7] = (_Float16)f1.w;
        if (qq == 0) *(half8*)&Xs0[k][tc * 8] = hv;
        else         *(half8*)&Xs1[k][tc * 8] = hv;

        half4v ov;
        #pragma unroll
        for (int j = 0; j < 4; ++j) {
            const int cm = tc * 4 + j;          // 0..31
            const int jj = cm - 3;
            const int d  = jj >> 3;
            const int mm = jj & 7;
            const float rsel = (d == 0) ? rx : ((d == 1) ? ry : rz);
            const float f2 = __int_as_float(0x3E22F983 + ((mm & 3) << 23));
            const float arg = fmaf(rsel, f2, (mm >= 4) ? 0.25f : 0.0f);
#if __has_builtin(__builtin_amdgcn_sinf)
            const float sv = __builtin_amdgcn_sinf(arg);
#else
            const float sv = __sinf(arg * 6.2831853071795864f);
#endif
            float v = (cm < 3) ? ((cm == 0) ? rx : ((cm == 1) ? ry : rz)) : sv;
            v = (cm == 27) ? 1.0f : ((cm > 27) ? 0.0f : v);
            ov[j] = (_Float16)v;
        }
        if (qq == 0) *(half4v*)&Xs0[k][64 + tc * 4] = ov;
        else         *(half4v*)&Xs1[k][64 + tc * 4] = ov;
    }
    __syncthreads();

    f32x4 acc[2][2][4];   // [qq][mt][nt]; lane: ch=(w*4+nt)*16+quad*4+r, pt=mt*16+l15

    // uniform (SGPR) weight bases + per-lane voffset -> saddr-form loads
    const int wu = __builtin_amdgcn_readfirstlane(w);
    const _Float16* __restrict__ w1w = w1p + (size_t)(wu * 4) * 512;
    const _Float16* __restrict__ w2w = w2p + (size_t)(wu * 4) * 512;
    const int lo8 = lane * 8;

    // ---- GEMM1: W1^T as A, Xs{0,1} as B -> acc (b1 via folded row) ----
    #pragma unroll
    for (int qq = 0; qq < 2; ++qq)
        #pragma unroll
        for (int mt = 0; mt < 2; ++mt)
            #pragma unroll
            for (int nt = 0; nt < 4; ++nt)
                acc[qq][mt][nt] = (f32x4){0.f, 0.f, 0.f, 0.f};

    #pragma unroll
    for (int kt = 0; kt < 3; ++kt) {
        const half8 xA0 = *(const half8*)&Xs0[l15][kt * 32 + quad * 8];
        const half8 xA1 = *(const half8*)&Xs0[16 + l15][kt * 32 + quad * 8];
        const half8 xB0 = *(const half8*)&Xs1[l15][kt * 32 + quad * 8];
        const half8 xB1 = *(const half8*)&Xs1[16 + l15][kt * 32 + quad * 8];
        #pragma unroll
        for (int nt = 0; nt < 4; ++nt) {
            const half8 wf = *(const half8*)(w1w + (kt * 16 + nt) * 512 + lo8);
            acc[0][0][nt] = __builtin_amdgcn_mfma_f32_16x16x32_f16(wf, xA0, acc[0][0][nt], 0, 0, 0);
            acc[0][1][nt] = __builtin_amdgcn_mfma_f32_16x16x32_f16(wf, xA1, acc[0][1][nt], 0, 0, 0);
            acc[1][0][nt] = __builtin_amdgcn_mfma_f32_16x16x32_f16(wf, xB0, acc[1][0][nt], 0, 0, 0);
            acc[1][1][nt] = __builtin_amdgcn_mfma_f32_16x16x32_f16(wf, xB1, acc[1][1][nt], 0, 0, 0);
        }
    }

    // ---- LN1 stats: packed pairwise accumulate + quad shfl + cross-warp LDS ----
    float mu[2][2], rs[2][2];
    #pragma unroll
    for (int qq = 0; qq < 2; ++qq)
        #pragma unroll
        for (int mt = 0; mt < 2; ++mt) {
            f32x2 sx  = {0.f, 0.f};
            f32x2 s2x = {0.f, 0.f};
            #pragma unroll
            for (int nt = 0; nt < 4; ++nt) {
                const f32x4 a4 = acc[qq][mt][nt];
                const f32x2 v0 = __builtin_shufflevector(a4, a4, 0, 1);
                const f32x2 v1 = __builtin_shufflevector(a4, a4, 2, 3);
                sx  = sx + v0;
                sx  = sx + v1;
                s2x = pkfma(v0, v0, s2x);
                s2x = pkfma(v1, v1, s2x);
            }
            float s  = sx.x + sx.y;
            float s2 = s2x.x + s2x.y;
            s  += __shfl_xor(s, 16, 64);  s  += __shfl_xor(s, 32, 64);
            s2 += __shfl_xor(s2, 16, 64); s2 += __shfl_xor(s2, 32, 64);
            if (quad == 0) sred[qq][mt][l15][w] = make_float2(s, s2);
        }
    __syncthreads();   // overlay fence (Xs reads done) + sred partials visible
    #pragma unroll
    for (int qq = 0; qq < 2; ++qq)
        #pragma unroll
        for (int mt = 0; mt < 2; ++mt) {
            const float4 pA = *(const float4*)&sred[qq][mt][l15][0];
            const float4 pB = *(const float4*)&sred[qq][mt][l15][2];
            const float S = pA.x + pA.z + pB.x + pB.z;
            const float Q = pA.y + pA.w + pB.y + pB.w;
            const float m_ = S * (1.0f / 256.0f);
            const float var = fmaf(Q, 1.0f / 256.0f, -m_ * m_);
            mu[qq][mt] = m_;
            rs[qq][mt] = __builtin_amdgcn_rsqf(var + 1e-5f);
        }

    // ---- LN1 apply + GeLU, packed f32, single f16 store into H16 ----
    #pragma unroll
    for (int nt = 0; nt < 4; ++nt) {
        const int chb = (w * 4 + nt) * 16 + quad * 4;
        const f32x2 gf0 = *(const f32x2*)&g1f[chb];
        const f32x2 gf1 = *(const f32x2*)&g1f[chb + 2];
        const f32x2 bf0 = *(const f32x2*)&be1f[chb];
        const f32x2 bf1 = *(const f32x2*)&be1f[chb + 2];
        #pragma unroll
        for (int qq = 0; qq < 2; ++qq)
            #pragma unroll
            for (int mt = 0; mt < 2; ++mt) {
                const f32x2 rs2  = {rs[qq][mt], rs[qq][mt]};
                const f32x2 nmu2 = {-mu[qq][mt], -mu[qq][mt]};
                const f32x2 A0 = gf0 * rs2;
                const f32x2 A1 = gf1 * rs2;
                const f32x2 B0 = pkfma(nmu2, A0, bf0);
                const f32x2 B1 = pkfma(nmu2, A1, bf1);
                const f32x4 a4 = acc[qq][mt][nt];
                const f32x2 y0 = pkfma(__builtin_shufflevector(a4, a4, 0, 1), A0, B0);
                const f32x2 y1 = pkfma(__builtin_shufflevector(a4, a4, 2, 3), A1, B1);
                const f32x2 o0 = gelu2(y0);
                const f32x2 o1 = gelu2(y1);
                half4v h;
                h[0] = (_Float16)o0.x; h[1] = (_Float16)o0.y;
                h[2] = (_Float16)o1.x; h[3] = (_Float16)o1.y;
                if (qq == 0) *(half4v*)&H16a[mt * 16 + l15][chb] = h;
                else         *(half4v*)&H16b[mt * 16 + l15][chb] = h;
            }
    }
    __syncthreads();   // H16 ready for GEMM2 B-reads

    // b2 fragments for GEMM2 C-init (short live range: load here, die at init)
    f32x4 bv[4];
    #pragma unroll
    for (int nt = 0; nt < 4; ++nt)
        bv[nt] = *(const f32x4*)&b2[(w * 4 + nt) * 16 + quad * 4];

    // ---- GEMM2: W2^T as A, H{a,b} as B; C-init = b2 (fold) ----
    #pragma unroll
    for (int qq = 0; qq < 2; ++qq)
        #pragma unroll
        for (int mt = 0; mt < 2; ++mt)
            #pragma unroll
            for (int nt = 0; nt < 4; ++nt)
                acc[qq][mt][nt] = bv[nt];

    #pragma unroll
    for (int kt = 0; kt < 8; ++kt) {
        const half8 hA0 = *(const half8*)&H16a[l15][kt * 32 + quad * 8];
        const half8 hA1 = *(const half8*)&H16a[16 + l15][kt * 32 + quad * 8];
        const half8 hB0 = *(const half8*)&H16b[l15][kt * 32 + quad * 8];
        const half8 hB1 = *(const half8*)&H16b[16 + l15][kt * 32 + quad * 8];
        #pragma unroll
        for (int nt = 0; nt < 4; ++nt) {
            const half8 wf = *(const half8*)(w2w + (kt * 16 + nt) * 512 + lo8);
            acc[0][0][nt] = __builtin_amdgcn_mfma_f32_16x16x32_f16(wf, hA0, acc[0][0][nt], 0, 0, 0);
            acc[0][1][nt] = __builtin_amdgcn_mfma_f32_16x16x32_f16(wf, hA1, acc[0][1][nt], 0, 0, 0);
            acc[1][0][nt] = __builtin_amdgcn_mfma_f32_16x16x32_f16(wf, hB0, acc[1][0][nt], 0, 0, 0);
            acc[1][1][nt] = __builtin_amdgcn_mfma_f32_16x16x32_f16(wf, hB1, acc[1][1][nt], 0, 0, 0);
        }
    }

    // ---- LN2 stats: packed pairwise (b2 already folded in) ----
    #pragma unroll
    for (int qq = 0; qq < 2; ++qq)
        #pragma unroll
        for (int mt = 0; mt < 2; ++mt) {
            f32x2 sx  = {0.f, 0.f};
            f32x2 s2x = {0.f, 0.f};
            #pragma unroll
            for (int nt = 0; nt < 4; ++nt) {
                const f32x4 a4 = acc[qq][mt][nt];
                const f32x2 v0 = __builtin_shufflevector(a4, a4, 0, 1);
                const f32x2 v1 = __builtin_shufflevector(a4, a4, 2, 3);
                sx  = sx + v0;
                sx  = sx + v1;
                s2x = pkfma(v0, v0, s2x);
                s2x = pkfma(v1, v1, s2x);
            }
            float s  = sx.x + sx.y;
            float s2 = s2x.x + s2x.y;
            s  += __shfl_xor(s, 16, 64);  s  += __shfl_xor(s, 32, 64);
            s2 += __shfl_xor(s2, 16, 64); s2 += __shfl_xor(s2, 32, 64);
            if (quad == 0) sred[qq][mt][l15][w] = make_float2(s, s2);
        }
    __syncthreads();   // ALL H16 B-reads done (in-place store safe) + partials
    #pragma unroll
    for (int qq = 0; qq < 2; ++qq)
        #pragma unroll
        for (int mt = 0; mt < 2; ++mt) {
            const float4 pA = *(const float4*)&sred[qq][mt][l15][0];
            const float4 pB = *(const float4*)&sred[qq][mt][l15][2];
            const float S = pA.x + pA.z + pB.x + pB.z;
            const float Q = pA.y + pA.w + pB.y + pB.w;
            const float m_ = S * (1.0f / 256.0f);
            const float var = fmaf(Q, 1.0f / 256.0f, -m_ * m_);
            mu[qq][mt] = m_;
            rs[qq][mt] = __builtin_amdgcn_rsqf(var + 1e-5f);
        }

    // ---- LN2 apply (no activation), packed f32, f16 store into H16 ----
    #pragma unroll
    for (int nt = 0; nt < 4; ++nt) {
        const int chb = (w * 4 + nt) * 16 + quad * 4;
        const f32x2 gf0 = *(const f32x2*)&g2f[chb];
        const f32x2 gf1 = *(const f32x2*)&g2f[chb + 2];
        const f32x2 bf0 = *(const f32x2*)&be2f[chb];
        const f32x2 bf1 = *(const f32x2*)&be2f[chb + 2];
        #pragma unroll
        for (int qq = 0; qq < 2; ++qq)
            #pragma unroll
            for (int mt = 0; mt < 2; ++mt) {
                const f32x2 rs2  = {rs[qq][mt], rs[qq][mt]};
                const f32x2 nmu2 = {-mu[qq][mt], -mu[qq][mt]};
                const f32x2 A0 = gf0 * rs2;
                const f32x2 A1 = gf1 * rs2;
                const f32x2 B0 = pkfma(nmu2, A0, bf0);
                const f32x2 B1 = pkfma(nmu2, A1, bf1);
                const f32x4 a4 = acc[qq][mt][nt];
                const f32x2 y0 = pkfma(__builtin_shufflevector(a4, a4, 0, 1), A0, B0);
                const f32x2 y1 = pkfma(__builtin_shufflevector(a4, a4, 2, 3), A1, B1);
                half4v h;
                h[0] = (_Float16)y0.x; h[1] = (_Float16)y0.y;
                h[2] = (_Float16)y1.x; h[3] = (_Float16)y1.y;
                if (qq == 0) *(half4v*)&H16a[mt * 16 + l15][chb] = h;
                else         *(half4v*)&H16b[mt * 16 + l15][chb] = h;
            }
    }
    __syncthreads();

    // ---- Phase 6: packed max over 32 points, all 256 threads (2 queries) ----
    {
        const int qq = t >> 7;
        const int tt = t & 127;
        const _Float16* Hf = qq ? &H16b[0][0] : &H16a[0][0];
        half2t mx = *(const half2t*)(Hf + 2 * tt);
        #pragma unroll
        for (int r = 1; r < KN; ++r) {
            const half2t v = *(const half2t*)(Hf + r * HSTR + 2 * tt);
            mx = __builtin_elementwise_max(mx, v);
        }
        float2 o2;
        o2.x = (float)mx[0];
        o2.y = (float)mx[1];
        *(float2*)&out0[(size_t)(q0 + qq) * C + 2 * tt] = o2;
    }
}

extern "C" void kernel_launch(void* const* d_in, const int* in_sizes, int n_in,
                              void* d_out, int out_size, void* d_ws, size_t ws_size,
                              hipStream_t stream) {
    const float* xyz = (const float*)d_in[0];
    const float* pf  = (const float*)d_in[1];
    const float* ctr = (const float*)d_in[2];
    const float* W1  = (const float*)d_in[3];
    const float* b1  = (const float*)d_in[4];
    const float* g1  = (const float*)d_in[5];
    const float* be1 = (const float*)d_in[6];
    const float* W2  = (const float*)d_in[7];
    const float* b2  = (const float*)d_in[8];
    const float* g2  = (const float*)d_in[9];
    const float* be2 = (const float*)d_in[10];

    float* out = (float*)d_out;
    _Float16* wp = (_Float16*)d_ws;
    float4* xyzw = (float4*)(wp + WP_ELEMS);   // 180224 B offset, 16-aligned; +2.06 MB

    prep_kernel<<<(WP_ELEMS + XYZW_ELEMS) / 256, 256, 0, stream>>>(W1, b1, W2, xyz, wp, xyzw);
    encoder_fused<<<NQ / 2, 256, 0, stream>>>(xyzw, pf, ctr,
                                              g1, be1, b2, g2, be2,
                                              wp, wp + W1P_ELEMS,
                                              out, out + PF_ELEMS);
}